// Round 1
// baseline (2032.974 us; speedup 1.0000x reference)
//
#include <hip/hip_runtime.h>
#include <cstddef>

#define HIDDEN 768
#define NHEADS 12
#define HDIM   64
#define BATCH  2
#define SEQ    2048
#define NROWS  (BATCH*SEQ)   // 4096

// ---------------------------------------------------------------------------
// Tiled fp32 GEMM: C[NROWS,768] = A[NROWS,768] @ W[768,768] + bias
// headsplit=1: write C into [B,H,S,D] layout (for Q/K/V)
// headsplit=0: write row-major [NROWS,HIDDEN] (final output)
// 64x64 block tile, 16x16 threads, 4x4 micro-tile, BK=16.
// ---------------------------------------------------------------------------
__global__ __launch_bounds__(256) void gemm768(const float* __restrict__ A,
                                               const float* __restrict__ W,
                                               const float* __restrict__ bias,
                                               float* __restrict__ C,
                                               int headsplit)
{
    __shared__ float As[64][20];   // stride 20 floats = 80 B (16B-aligned rows, 2-way banks)
    __shared__ float Bs[16][64];
    const int tid = threadIdx.x;
    const int tx = tid & 15, ty = tid >> 4;
    const int r0 = blockIdx.y * 64, n0 = blockIdx.x * 64;
    float c[4][4] = {};

    for (int k0 = 0; k0 < HIDDEN; k0 += 16) {
        {
            const int row = tid >> 2, kk = (tid & 3) << 2;
            const float4 av = *reinterpret_cast<const float4*>(&A[(size_t)(r0 + row) * HIDDEN + k0 + kk]);
            *reinterpret_cast<float4*>(&As[row][kk]) = av;
            const int krow = tid >> 4, n4 = (tid & 15) << 2;
            const float4 bv = *reinterpret_cast<const float4*>(&W[(size_t)(k0 + krow) * HIDDEN + n0 + n4]);
            *reinterpret_cast<float4*>(&Bs[krow][n4]) = bv;
        }
        __syncthreads();
#pragma unroll
        for (int kk = 0; kk < 16; ++kk) {
            float a[4], b[4];
#pragma unroll
            for (int i = 0; i < 4; ++i) a[i] = As[ty * 4 + i][kk];
#pragma unroll
            for (int j = 0; j < 4; ++j) b[j] = Bs[kk][tx * 4 + j];
#pragma unroll
            for (int i = 0; i < 4; ++i)
#pragma unroll
                for (int j = 0; j < 4; ++j) c[i][j] += a[i] * b[j];
        }
        __syncthreads();
    }

#pragma unroll
    for (int i = 0; i < 4; ++i) {
        const int r = r0 + ty * 4 + i;
#pragma unroll
        for (int j = 0; j < 4; ++j) {
            const int col = n0 + tx * 4 + j;
            const float v = c[i][j] + bias[col];
            if (headsplit) {
                const int bb = r >> 11, ss = r & (SEQ - 1);
                const int hh = col >> 6, dd = col & (HDIM - 1);
                C[(((size_t)bb * NHEADS + hh) * SEQ + ss) * HDIM + dd] = v;
            } else {
                C[(size_t)r * HIDDEN + col] = v;
            }
        }
    }
}

// ---------------------------------------------------------------------------
// Flash-style attention (no 1/sqrt(d) scale, full bidirectional softmax).
// One block = one (b, h, 64-row q-tile). 256 threads: thread t handles
// q-row r = t>>2, quarter q4 = t&3 (16-elem d-slice / j-slice).
// Q row in registers (64 floats, duplicated x4 across the quad).
// K/V/P tiles in LDS, stride 65 to break bank conflicts.
// Online softmax state (m, l) per row; quad reductions via __shfl_xor.
// ---------------------------------------------------------------------------
__global__ __launch_bounds__(256) void attn64(const float* __restrict__ Q,
                                              const float* __restrict__ K,
                                              const float* __restrict__ V,
                                              float* __restrict__ O)
{
    __shared__ float Ks[64][65];
    __shared__ float Vs[64][65];
    __shared__ float Ps[64][65];
    const int tid = threadIdx.x;
    const int r  = tid >> 2;   // q-row in tile
    const int q4 = tid & 3;    // quarter (16-wide slice)
    const int q0 = blockIdx.x * 64;
    const int h  = blockIdx.y;
    const int b  = blockIdx.z;
    const size_t base = ((size_t)b * NHEADS + h) * (size_t)SEQ * HDIM;

    // Q row -> registers
    float q_reg[64];
    {
        const float* qp = &Q[base + (size_t)(q0 + r) * HDIM];
#pragma unroll
        for (int u = 0; u < 16; ++u) {
            const float4 t = *reinterpret_cast<const float4*>(qp + u * 4);
            q_reg[u * 4 + 0] = t.x; q_reg[u * 4 + 1] = t.y;
            q_reg[u * 4 + 2] = t.z; q_reg[u * 4 + 3] = t.w;
        }
    }

    float acc[16] = {};
    float m = -1e30f, l = 0.f;

    for (int t0 = 0; t0 < SEQ; t0 += 64) {
        __syncthreads();   // protect K/V/P reuse from previous iteration
        {
            const int row = tid >> 2, dd = (tid & 3) << 4;
            const float* kp = &K[base + (size_t)(t0 + row) * HDIM + dd];
            const float* vp = &V[base + (size_t)(t0 + row) * HDIM + dd];
#pragma unroll
            for (int u = 0; u < 4; ++u) {
                const float4 kv = *reinterpret_cast<const float4*>(kp + u * 4);
                Ks[row][dd + u * 4 + 0] = kv.x; Ks[row][dd + u * 4 + 1] = kv.y;
                Ks[row][dd + u * 4 + 2] = kv.z; Ks[row][dd + u * 4 + 3] = kv.w;
                const float4 vv = *reinterpret_cast<const float4*>(vp + u * 4);
                Vs[row][dd + u * 4 + 0] = vv.x; Vs[row][dd + u * 4 + 1] = vv.y;
                Vs[row][dd + u * 4 + 2] = vv.z; Vs[row][dd + u * 4 + 3] = vv.w;
            }
        }
        __syncthreads();

        // scores for this thread's 16 j's (full 64-d dot from registers)
        float sv[16];
        float tmax = -1e30f;
#pragma unroll
        for (int jj = 0; jj < 16; ++jj) {
            const int j = q4 * 16 + jj;
            float s = 0.f;
#pragma unroll
            for (int d = 0; d < 64; ++d) s += q_reg[d] * Ks[j][d];
            sv[jj] = s;
            tmax = fmaxf(tmax, s);
        }
        // row max across the quad
        tmax = fmaxf(tmax, __shfl_xor(tmax, 1));
        tmax = fmaxf(tmax, __shfl_xor(tmax, 2));
        const float m_new = fmaxf(m, tmax);
        const float scale = __expf(m - m_new);
        float lsum = 0.f;
#pragma unroll
        for (int jj = 0; jj < 16; ++jj) {
            const float p = __expf(sv[jj] - m_new);
            Ps[r][q4 * 16 + jj] = p;
            lsum += p;
        }
        lsum += __shfl_xor(lsum, 1);
        lsum += __shfl_xor(lsum, 2);
        l = l * scale + lsum;
        m = m_new;
#pragma unroll
        for (int dd = 0; dd < 16; ++dd) acc[dd] *= scale;
        __syncthreads();   // P visible to all

        // acc[d-slice] += P[r][:] @ V[:, d-slice]
#pragma unroll 8
        for (int j = 0; j < 64; ++j) {
            const float p = Ps[r][j];
#pragma unroll
            for (int dd = 0; dd < 16; ++dd)
                acc[dd] += p * Vs[j][q4 * 16 + dd];
        }
    }

    const float inv_l = 1.f / l;
    // write back to [B, S, HIDDEN] (heads re-interleaved)
    float* op = &O[((size_t)b * SEQ + q0 + r) * HIDDEN + h * HDIM + q4 * 16];
#pragma unroll
    for (int dd = 0; dd < 16; ++dd) op[dd] = acc[dd] * inv_l;
}

// ---------------------------------------------------------------------------
extern "C" void kernel_launch(void* const* d_in, const int* in_sizes, int n_in,
                              void* d_out, int out_size, void* d_ws, size_t ws_size,
                              hipStream_t stream)
{
    const float* x  = (const float*)d_in[0];
    const float* Wq = (const float*)d_in[1];
    const float* bq = (const float*)d_in[2];
    const float* Wk = (const float*)d_in[3];
    const float* bk = (const float*)d_in[4];
    const float* Wv = (const float*)d_in[5];
    const float* bv = (const float*)d_in[6];
    const float* Wo = (const float*)d_in[7];
    const float* bo = (const float*)d_in[8];
    float* out = (float*)d_out;

    const size_t per = (size_t)BATCH * NHEADS * SEQ * HDIM;  // 3,145,728 floats
    float* Q  = (float*)d_ws;
    float* K  = Q + per;
    float* V  = K + per;
    float* Oa = V + per;   // attention output, [B,S,HIDDEN]; total ws use ~50.3 MB

    dim3 gg(HIDDEN / 64, NROWS / 64);
    gemm768<<<gg, 256, 0, stream>>>(x, Wq, bq, Q, 1);
    gemm768<<<gg, 256, 0, stream>>>(x, Wk, bk, K, 1);
    gemm768<<<gg, 256, 0, stream>>>(x, Wv, bv, V, 1);
    attn64<<<dim3(SEQ / 64, NHEADS, BATCH), 256, 0, stream>>>(Q, K, V, Oa);
    gemm768<<<gg, 256, 0, stream>>>(Oa, Wo, bo, out, 0);
}

// Round 5
// 179.676 us; speedup vs baseline: 11.3147x; 11.3147x over previous
//
#include <hip/hip_runtime.h>
#include <cstddef>

#define HIDDEN 768
#define NHEADS 12
#define HDIM   64
#define BATCH  2
#define SEQ    2048
#define NROWS  (BATCH*SEQ)   // 4096

typedef float f32x4 __attribute__((ext_vector_type(4)));
typedef short bf16x8 __attribute__((ext_vector_type(8)));

__device__ __forceinline__ unsigned short f2bf(float f){
    unsigned u = __builtin_bit_cast(unsigned, f);
    u = u + 0x7FFFu + ((u >> 16) & 1u);   // RNE
    return (unsigned short)(u >> 16);
}

// ---------------------------------------------------------------------------
// Elementwise fp32 -> bf16 (vectorized float4 -> ushort4)
// ---------------------------------------------------------------------------
__global__ __launch_bounds__(256) void cvt_bf16(const float* __restrict__ in,
                                                unsigned short* __restrict__ out,
                                                int n4)
{
    const int i = blockIdx.x * 256 + threadIdx.x;
    if (i >= n4) return;
    const float4 v = reinterpret_cast<const float4*>(in)[i];
    ushort4 o;
    o.x = f2bf(v.x); o.y = f2bf(v.y); o.z = f2bf(v.z); o.w = f2bf(v.w);
    reinterpret_cast<ushort4*>(out)[i] = o;
}

// ---------------------------------------------------------------------------
// 768x768 fp32 W -> bf16 W^T (n-major) via LDS tile transpose.
// ---------------------------------------------------------------------------
__global__ __launch_bounds__(256) void transpose_cvt(const float* __restrict__ W,
                                                     unsigned short* __restrict__ Wt)
{
    __shared__ unsigned short t[64][66];
    const int k0 = blockIdx.y * 64, n0 = blockIdx.x * 64;
    const int row = threadIdx.x >> 2;        // 0..63
    const int c0  = (threadIdx.x & 3) * 16;  // 0,16,32,48
#pragma unroll
    for (int j = 0; j < 16; j += 4) {
        const float4 v = *reinterpret_cast<const float4*>(&W[(size_t)(k0 + row) * HIDDEN + n0 + c0 + j]);
        t[row][c0 + j + 0] = f2bf(v.x);
        t[row][c0 + j + 1] = f2bf(v.y);
        t[row][c0 + j + 2] = f2bf(v.z);
        t[row][c0 + j + 3] = f2bf(v.w);
    }
    __syncthreads();
#pragma unroll
    for (int j = 0; j < 16; j += 4) {
        ushort4 o;
        o.x = t[c0 + j + 0][row];
        o.y = t[c0 + j + 1][row];
        o.z = t[c0 + j + 2][row];
        o.w = t[c0 + j + 3][row];
        *reinterpret_cast<ushort4*>(&Wt[(size_t)(n0 + row) * HIDDEN + k0 + c0 + j]) = o;
    }
}

// ---------------------------------------------------------------------------
// bf16 MFMA GEMM: C[4096,768] = A[4096,768] @ Wt^T + bias
//   A bf16 row-major, Wt bf16 n-major (transposed), fp32 accumulate.
// mode 0: bf16 out, [B,H,S,D]   (Q, K)
// mode 1: bf16 out, [B,H,D,S]   (V transposed)
// mode 2: fp32 out, row-major   (final)
// 64x64 tile, 4 waves (2x2), each wave 32x32 via 2x2 MFMA frags, BK=32.
// ---------------------------------------------------------------------------
__global__ __launch_bounds__(256) void gemm_mfma(const unsigned short* __restrict__ A,
                                                 const unsigned short* __restrict__ Wt,
                                                 const float* __restrict__ bias,
                                                 void* __restrict__ Cout, int mode)
{
    __shared__ unsigned short As[64][40];  // 80 B rows: 16B-aligned, 2-way banks
    __shared__ unsigned short Bs[64][40];
    const int tid = threadIdx.x;
    const int m0 = blockIdx.y * 64, n0 = blockIdx.x * 64;
    const int l = tid & 63, w = tid >> 6;
    const int wm = w >> 1, wn = w & 1;
    const int l15 = l & 15, lg = l >> 4;
    const int srow = tid >> 2, sch = (tid & 3) * 8;

    f32x4 acc[2][2] = {};

    for (int k0 = 0; k0 < HIDDEN; k0 += 32) {
        const uint4 av = *reinterpret_cast<const uint4*>(&A [(size_t)(m0 + srow) * HIDDEN + k0 + sch]);
        const uint4 bv = *reinterpret_cast<const uint4*>(&Wt[(size_t)(n0 + srow) * HIDDEN + k0 + sch]);
        __syncthreads();   // previous iteration's reads complete
        *reinterpret_cast<uint4*>(&As[srow][sch]) = av;
        *reinterpret_cast<uint4*>(&Bs[srow][sch]) = bv;
        __syncthreads();
        bf16x8 af[2], bf[2];
#pragma unroll
        for (int mi = 0; mi < 2; ++mi)
            af[mi] = *reinterpret_cast<const bf16x8*>(&As[wm * 32 + mi * 16 + l15][lg * 8]);
#pragma unroll
        for (int ni = 0; ni < 2; ++ni)
            bf[ni] = *reinterpret_cast<const bf16x8*>(&Bs[wn * 32 + ni * 16 + l15][lg * 8]);
#pragma unroll
        for (int mi = 0; mi < 2; ++mi)
#pragma unroll
            for (int ni = 0; ni < 2; ++ni)
                acc[mi][ni] = __builtin_amdgcn_mfma_f32_16x16x32_bf16(af[mi], bf[ni], acc[mi][ni], 0, 0, 0);
    }

#pragma unroll
    for (int mi = 0; mi < 2; ++mi) {
#pragma unroll
        for (int ni = 0; ni < 2; ++ni) {
#pragma unroll
            for (int r = 0; r < 4; ++r) {
                const int row = m0 + wm * 32 + mi * 16 + lg * 4 + r;   // C row = (lane>>4)*4+reg (m89)
                const int col = n0 + wn * 32 + ni * 16 + l15;          // C col = lane&15
                const float v = acc[mi][ni][r] + bias[col];
                if (mode == 0) {
                    const int b = row >> 11, s = row & (SEQ - 1);
                    const int hh = col >> 6, d = col & (HDIM - 1);
                    ((unsigned short*)Cout)[(((size_t)b * NHEADS + hh) * SEQ + s) * HDIM + d] = f2bf(v);
                } else if (mode == 1) {
                    const int b = row >> 11, s = row & (SEQ - 1);
                    const int hh = col >> 6, d = col & (HDIM - 1);
                    ((unsigned short*)Cout)[(((size_t)b * NHEADS + hh) * HDIM + d) * SEQ + s] = f2bf(v);
                } else {
                    ((float*)Cout)[(size_t)row * HIDDEN + col] = v;
                }
            }
        }
    }
}

// ---------------------------------------------------------------------------
// Flash attention, bf16 MFMA (no 1/sqrt(d) scale per reference).
// Block = (b, h, 64 q-rows); 4 waves x 16 q-rows. Q frags in registers.
// K tile [64][72] and V^T tile [64 d][72 j] in LDS (144 B stride = 2-way banks).
// Online softmax on C-layout regs; P via per-wave LDS strip (in-wave ordered).
// ---------------------------------------------------------------------------
__global__ __launch_bounds__(256) void attn_mfma(const unsigned short* __restrict__ Q,
                                                 const unsigned short* __restrict__ K,
                                                 const unsigned short* __restrict__ Vt,
                                                 unsigned short* __restrict__ O)
{
    __shared__ unsigned short Ks[64][72];
    __shared__ unsigned short Vs[64][72];       // [d][j]
    __shared__ unsigned short Ps[4][16][72];    // per-wave P strip [qlocal][j]
    const int tid = threadIdx.x;
    const int l = tid & 63, w = tid >> 6;
    const int l15 = l & 15, lg = l >> 4;
    const int q0 = blockIdx.x * 64;
    const int h = blockIdx.y, b = blockIdx.z;
    const size_t base = ((size_t)b * NHEADS + h) * (size_t)SEQ * HDIM;  // Q, K, Vt

    // Q fragments: lane l holds Q[q0+w*16+(l&15)][(l>>4)*8 + i (+32)]
    bf16x8 qf[2];
    {
        const unsigned short* qp = &Q[base + (size_t)(q0 + w * 16 + l15) * HDIM + lg * 8];
        qf[0] = *reinterpret_cast<const bf16x8*>(qp);
        qf[1] = *reinterpret_cast<const bf16x8*>(qp + 32);
    }

    f32x4 accO[4] = {};
    float mrow[4], lrow[4];
#pragma unroll
    for (int r = 0; r < 4; ++r) { mrow[r] = -1e30f; lrow[r] = 0.f; }

    const int sr0 = tid >> 3, sc0 = (tid & 7) * 8;   // staging: 2 chunks/array/thread

    for (int t0 = 0; t0 < SEQ; t0 += 64) {
        const uint4 kv0 = *reinterpret_cast<const uint4*>(&K [base + (size_t)(t0 + sr0)      * HDIM + sc0]);
        const uint4 kv1 = *reinterpret_cast<const uint4*>(&K [base + (size_t)(t0 + 32 + sr0) * HDIM + sc0]);
        const uint4 vv0 = *reinterpret_cast<const uint4*>(&Vt[base + (size_t)sr0        * SEQ + t0 + sc0]);
        const uint4 vv1 = *reinterpret_cast<const uint4*>(&Vt[base + (size_t)(32 + sr0) * SEQ + t0 + sc0]);
        __syncthreads();   // previous iteration's LDS reads complete
        *reinterpret_cast<uint4*>(&Ks[sr0][sc0])      = kv0;
        *reinterpret_cast<uint4*>(&Ks[32 + sr0][sc0]) = kv1;
        *reinterpret_cast<uint4*>(&Vs[sr0][sc0])      = vv0;
        *reinterpret_cast<uint4*>(&Vs[32 + sr0][sc0]) = vv1;
        __syncthreads();

        // QK^T: S_strip(16x64) = Q_strip @ K_tile^T
        f32x4 sc[4] = {};
#pragma unroll
        for (int kb = 0; kb < 2; ++kb) {
#pragma unroll
            for (int jb = 0; jb < 4; ++jb) {
                const bf16x8 kf = *reinterpret_cast<const bf16x8*>(&Ks[jb * 16 + l15][lg * 8 + kb * 32]);
                sc[jb] = __builtin_amdgcn_mfma_f32_16x16x32_bf16(qf[kb], kf, sc[jb], 0, 0, 0);
            }
        }

        // online softmax (row = lg*4+r lives in 16-lane group; width-16 reduce)
#pragma unroll
        for (int r = 0; r < 4; ++r) {
            float t = fmaxf(fmaxf(sc[0][r], sc[1][r]), fmaxf(sc[2][r], sc[3][r]));
            t = fmaxf(t, __shfl_xor(t, 1));
            t = fmaxf(t, __shfl_xor(t, 2));
            t = fmaxf(t, __shfl_xor(t, 4));
            t = fmaxf(t, __shfl_xor(t, 8));
            const float mnew = fmaxf(mrow[r], t);
            const float scale = __expf(mrow[r] - mnew);
            float ls = 0.f;
#pragma unroll
            for (int jb = 0; jb < 4; ++jb) {
                const float p = __expf(sc[jb][r] - mnew);
                sc[jb][r] = p;
                ls += p;
            }
            ls += __shfl_xor(ls, 1);
            ls += __shfl_xor(ls, 2);
            ls += __shfl_xor(ls, 4);
            ls += __shfl_xor(ls, 8);
            lrow[r] = lrow[r] * scale + ls;
            mrow[r] = mnew;
#pragma unroll
            for (int db = 0; db < 4; ++db) accO[db][r] *= scale;
#pragma unroll
            for (int jb = 0; jb < 4; ++jb)
                Ps[w][lg * 4 + r][jb * 16 + l15] = f2bf(sc[jb][r]);
        }

        // PV: accO(16x64) += P_strip @ V_tile   (B from V^T rows: contiguous)
#pragma unroll
        for (int jb2 = 0; jb2 < 2; ++jb2) {
            const bf16x8 pf = *reinterpret_cast<const bf16x8*>(&Ps[w][l15][lg * 8 + jb2 * 32]);
#pragma unroll
            for (int db = 0; db < 4; ++db) {
                const bf16x8 vf = *reinterpret_cast<const bf16x8*>(&Vs[db * 16 + l15][lg * 8 + jb2 * 32]);
                accO[db] = __builtin_amdgcn_mfma_f32_16x16x32_bf16(pf, vf, accO[db], 0, 0, 0);
            }
        }
    }

    // epilogue: O[b, s, h*64+d] bf16
#pragma unroll
    for (int r = 0; r < 4; ++r) {
        const float inv = 1.f / lrow[r];
        const size_t orow = ((size_t)b * SEQ + q0 + w * 16 + lg * 4 + r) * HIDDEN + h * HDIM;
#pragma unroll
        for (int db = 0; db < 4; ++db)
            O[orow + db * 16 + l15] = f2bf(accO[db][r] * inv);
    }
}

// ---------------------------------------------------------------------------
extern "C" void kernel_launch(void* const* d_in, const int* in_sizes, int n_in,
                              void* d_out, int out_size, void* d_ws, size_t ws_size,
                              hipStream_t stream)
{
    const float* x  = (const float*)d_in[0];
    const float* Wq = (const float*)d_in[1];
    const float* bq = (const float*)d_in[2];
    const float* Wk = (const float*)d_in[3];
    const float* bk = (const float*)d_in[4];
    const float* Wv = (const float*)d_in[5];
    const float* bv = (const float*)d_in[6];
    const float* Wo = (const float*)d_in[7];
    const float* bo = (const float*)d_in[8];
    float* out = (float*)d_out;

    unsigned short* p = (unsigned short*)d_ws;
    const size_t szX = (size_t)NROWS * HIDDEN;          // 3,145,728 elems
    const size_t szW = (size_t)HIDDEN * HIDDEN;         //   589,824 elems
    const size_t szH = (size_t)BATCH * NHEADS * SEQ * HDIM;  // 3,145,728 elems
    unsigned short* xb  = p;              p += szX;
    unsigned short* Wqt = p;              p += szW;
    unsigned short* Wkt = p;              p += szW;
    unsigned short* Wvt = p;              p += szW;
    unsigned short* Wot = p;              p += szW;
    unsigned short* Qb  = p;              p += szH;
    unsigned short* Kb  = p;              p += szH;
    unsigned short* Vtb = p;              p += szH;
    unsigned short* Oab = p;              p += szX;     // total ~36.2 MB

    cvt_bf16<<<(int)(szX / 4 + 255) / 256, 256, 0, stream>>>(x, xb, (int)(szX / 4));
    dim3 tg(HIDDEN / 64, HIDDEN / 64);
    transpose_cvt<<<tg, 256, 0, stream>>>(Wq, Wqt);
    transpose_cvt<<<tg, 256, 0, stream>>>(Wk, Wkt);
    transpose_cvt<<<tg, 256, 0, stream>>>(Wv, Wvt);
    transpose_cvt<<<tg, 256, 0, stream>>>(Wo, Wot);

    dim3 gg(HIDDEN / 64, NROWS / 64);
    gemm_mfma<<<gg, 256, 0, stream>>>(xb, Wqt, bq, Qb, 0);
    gemm_mfma<<<gg, 256, 0, stream>>>(xb, Wkt, bk, Kb, 0);
    gemm_mfma<<<gg, 256, 0, stream>>>(xb, Wvt, bv, Vtb, 1);

    attn_mfma<<<dim3(SEQ / 64, NHEADS, BATCH), 256, 0, stream>>>(Qb, Kb, Vtb, Oab);

    gemm_mfma<<<gg, 256, 0, stream>>>(Oab, Wot, bo, out, 2);
}

// Round 8
// 167.948 us; speedup vs baseline: 12.1048x; 1.0698x over previous
//
#include <hip/hip_runtime.h>
#include <cstddef>

#define HIDDEN 768
#define NHEADS 12
#define HDIM   64
#define BATCH  2
#define SEQ    2048
#define NROWS  (BATCH*SEQ)   // 4096
#define LOG2E  1.4426950408889634f

typedef float f32x4 __attribute__((ext_vector_type(4)));
typedef short bf16x8 __attribute__((ext_vector_type(8)));

__device__ __forceinline__ float fast_exp2(float x){   // v_exp_f32: D = 2^S0
    return __builtin_amdgcn_exp2f(x);
}

__device__ __forceinline__ unsigned short f2bf(float f){   // RNE (one-time prep paths)
    unsigned u = __builtin_bit_cast(unsigned, f);
    u = u + 0x7FFFu + ((u >> 16) & 1u);
    return (unsigned short)(u >> 16);
}
__device__ __forceinline__ unsigned short f2bf_hu(float f){ // round-half-up, 2 ops (hot path)
    unsigned u = __builtin_bit_cast(unsigned, f);
    return (unsigned short)((u + 0x8000u) >> 16);
}

// async global->LDS, 16B per lane; lds base must be wave-uniform (lane i writes base+i*16)
__device__ __forceinline__ void gl_lds16(const unsigned short* g, unsigned short* l){
    __builtin_amdgcn_global_load_lds(
        (const __attribute__((address_space(1))) unsigned int*)g,
        (__attribute__((address_space(3))) unsigned int*)l, 16, 0, 0);
}

// ---------------------------------------------------------------------------
// Elementwise fp32 -> bf16
// ---------------------------------------------------------------------------
__global__ __launch_bounds__(256) void cvt_bf16(const float* __restrict__ in,
                                                unsigned short* __restrict__ out,
                                                int n4)
{
    const int i = blockIdx.x * 256 + threadIdx.x;
    if (i >= n4) return;
    const float4 v = reinterpret_cast<const float4*>(in)[i];
    ushort4 o;
    o.x = f2bf(v.x); o.y = f2bf(v.y); o.z = f2bf(v.z); o.w = f2bf(v.w);
    reinterpret_cast<ushort4*>(out)[i] = o;
}

// ---------------------------------------------------------------------------
// 768x768 fp32 W -> bf16 W^T (n-major)
// ---------------------------------------------------------------------------
__global__ __launch_bounds__(256) void transpose_cvt(const float* __restrict__ W,
                                                     unsigned short* __restrict__ Wt)
{
    __shared__ unsigned short t[64][66];
    const int k0 = blockIdx.y * 64, n0 = blockIdx.x * 64;
    const int row = threadIdx.x >> 2;
    const int c0  = (threadIdx.x & 3) * 16;
#pragma unroll
    for (int j = 0; j < 16; j += 4) {
        const float4 v = *reinterpret_cast<const float4*>(&W[(size_t)(k0 + row) * HIDDEN + n0 + c0 + j]);
        t[row][c0 + j + 0] = f2bf(v.x);
        t[row][c0 + j + 1] = f2bf(v.y);
        t[row][c0 + j + 2] = f2bf(v.z);
        t[row][c0 + j + 3] = f2bf(v.w);
    }
    __syncthreads();
#pragma unroll
    for (int j = 0; j < 16; j += 4) {
        ushort4 o;
        o.x = t[c0 + j + 0][row];
        o.y = t[c0 + j + 1][row];
        o.z = t[c0 + j + 2][row];
        o.w = t[c0 + j + 3][row];
        *reinterpret_cast<ushort4*>(&Wt[(size_t)(n0 + row) * HIDDEN + k0 + c0 + j]) = o;
    }
}

// ---------------------------------------------------------------------------
// bf16 MFMA GEMM: C[4096,768] = (A[4096,768] @ Wt^T + bias) * scale
// 64x96 tile, BK=64, global_load_lds(16B) staging, XOR-swizzled linear LDS.
// 4 waves 2x2; wave tile 32x48 (2x3 frags of 16x16). Grid (8,64)=512 = 2/CU.
// mode 0: bf16 out [B,H,S,D]; 1: bf16 out [B,H,D,S]; 2: fp32 out row-major.
// ---------------------------------------------------------------------------
__global__ __launch_bounds__(256) void gemm_mfma(const unsigned short* __restrict__ A,
                                                 const unsigned short* __restrict__ Wt,
                                                 const float* __restrict__ bias,
                                                 void* __restrict__ Cout, int mode,
                                                 float scale)
{
    __shared__ unsigned short As[64 * 64];   // 8 KB, linear, swizzled
    __shared__ unsigned short Bs[96 * 64];   // 12 KB
    const int tid = threadIdx.x;
    const int l = tid & 63, w = tid >> 6;
    const int wm = w >> 1, wn = w & 1;
    const int l15 = l & 15, lg = l >> 4;
    const int srow = l >> 3, sslot = l & 7;       // staging: 8 lanes per 128B row
    const int m0 = blockIdx.y * 64, n0 = blockIdx.x * 96;

    f32x4 acc[2][3] = {};

    for (int k0 = 0; k0 < HIDDEN; k0 += 64) {
        __syncthreads();   // previous iteration's LDS reads complete
#pragma unroll
        for (int a = 0; a < 2; ++a) {             // A: 2 insts x 4 waves = 64 rows
            const int row = (a * 4 + w) * 8 + srow;
            const int sl = sslot ^ (row & 7);     // inverse-swizzled source (rule 21)
            gl_lds16(&A[(size_t)(m0 + row) * HIDDEN + k0 + sl * 8], &As[(a * 4 + w) * 512]);
        }
#pragma unroll
        for (int b = 0; b < 3; ++b) {             // B: 3 insts = 96 rows
            const int row = (b * 4 + w) * 8 + srow;
            const int sl = sslot ^ (row & 7);
            gl_lds16(&Wt[(size_t)(n0 + row) * HIDDEN + k0 + sl * 8], &Bs[(b * 4 + w) * 512]);
        }
        __syncthreads();   // vmcnt(0) drained by compiler before barrier

#pragma unroll
        for (int kk = 0; kk < 2; ++kk) {
            bf16x8 af[2], bfr[3];
#pragma unroll
            for (int mi = 0; mi < 2; ++mi) {
                const int r = wm * 32 + mi * 16 + l15;
                af[mi] = *reinterpret_cast<const bf16x8*>(&As[r * 64 + ((lg * 8 + kk * 32) ^ ((r & 7) << 3))]);
            }
#pragma unroll
            for (int ni = 0; ni < 3; ++ni) {
                const int r = wn * 48 + ni * 16 + l15;
                bfr[ni] = *reinterpret_cast<const bf16x8*>(&Bs[r * 64 + ((lg * 8 + kk * 32) ^ ((r & 7) << 3))]);
            }
#pragma unroll
            for (int mi = 0; mi < 2; ++mi)
#pragma unroll
                for (int ni = 0; ni < 3; ++ni)
                    acc[mi][ni] = __builtin_amdgcn_mfma_f32_16x16x32_bf16(af[mi], bfr[ni], acc[mi][ni], 0, 0, 0);
        }
    }

#pragma unroll
    for (int mi = 0; mi < 2; ++mi) {
#pragma unroll
        for (int ni = 0; ni < 3; ++ni) {
#pragma unroll
            for (int rr = 0; rr < 4; ++rr) {
                const int row = m0 + wm * 32 + mi * 16 + lg * 4 + rr;   // C row (m89)
                const int col = n0 + wn * 48 + ni * 16 + l15;           // C col
                const float v = (acc[mi][ni][rr] + bias[col]) * scale;
                if (mode == 0) {
                    const int b = row >> 11, s = row & (SEQ - 1);
                    const int hh = col >> 6, d = col & (HDIM - 1);
                    ((unsigned short*)Cout)[(((size_t)b * NHEADS + hh) * SEQ + s) * HDIM + d] = f2bf(v);
                } else if (mode == 1) {
                    const int b = row >> 11, s = row & (SEQ - 1);
                    const int hh = col >> 6, d = col & (HDIM - 1);
                    ((unsigned short*)Cout)[(((size_t)b * NHEADS + hh) * HDIM + d) * SEQ + s] = f2bf(v);
                } else {
                    ((float*)Cout)[(size_t)row * HIDDEN + col] = v;
                }
            }
        }
    }
}

// ---------------------------------------------------------------------------
// Flash attention, bf16 MFMA. Q comes pre-scaled by log2(e) -> exp2-domain
// softmax. K/V staged via global_load_lds into swizzled linear LDS.
// Block = (b, h, 64 q-rows); 4 waves x 16 q-rows.
// ---------------------------------------------------------------------------
__global__ __launch_bounds__(256) void attn_mfma(const unsigned short* __restrict__ Q,
                                                 const unsigned short* __restrict__ K,
                                                 const unsigned short* __restrict__ Vt,
                                                 unsigned short* __restrict__ O)
{
    __shared__ unsigned short Ks[64 * 64];      // 8 KB linear swizzled [j][k]
    __shared__ unsigned short Vs[64 * 64];      // 8 KB linear swizzled [d][j]
    __shared__ unsigned short Ps[4][16][72];    // per-wave P strip (padded)
    const int tid = threadIdx.x;
    const int l = tid & 63, w = tid >> 6;
    const int l15 = l & 15, lg = l >> 4;
    const int srow = l >> 3, sslot = l & 7;
    const int q0 = blockIdx.x * 64;
    const int h = blockIdx.y, b = blockIdx.z;
    const size_t base = ((size_t)b * NHEADS + h) * (size_t)SEQ * HDIM;

    bf16x8 qf[2];
    {
        const unsigned short* qp = &Q[base + (size_t)(q0 + w * 16 + l15) * HDIM + lg * 8];
        qf[0] = *reinterpret_cast<const bf16x8*>(qp);
        qf[1] = *reinterpret_cast<const bf16x8*>(qp + 32);
    }

    f32x4 accO[4] = {};
    float mrow[4], lrow[4];
#pragma unroll
    for (int r = 0; r < 4; ++r) { mrow[r] = -1e30f; lrow[r] = 0.f; }

    for (int t0 = 0; t0 < SEQ; t0 += 64) {
        __syncthreads();   // previous tile's LDS reads complete
#pragma unroll
        for (int a = 0; a < 2; ++a) {
            const int row = (a * 4 + w) * 8 + srow;
            const int sl = sslot ^ (row & 7);
            gl_lds16(&K [base + (size_t)(t0 + row) * HDIM + sl * 8], &Ks[(a * 4 + w) * 512]);
            gl_lds16(&Vt[base + (size_t)row * SEQ + t0 + sl * 8],    &Vs[(a * 4 + w) * 512]);
        }
        __syncthreads();

        // QK^T: S_strip(16x64)
        f32x4 sc[4] = {};
#pragma unroll
        for (int kb = 0; kb < 2; ++kb) {
#pragma unroll
            for (int jb = 0; jb < 4; ++jb) {
                const int kr = jb * 16 + l15;
                const bf16x8 kf = *reinterpret_cast<const bf16x8*>(&Ks[kr * 64 + ((lg * 8 + kb * 32) ^ ((kr & 7) << 3))]);
                sc[jb] = __builtin_amdgcn_mfma_f32_16x16x32_bf16(qf[kb], kf, sc[jb], 0, 0, 0);
            }
        }

        // exp2-domain online softmax (scores already x log2e via Q pre-scale)
#pragma unroll
        for (int r = 0; r < 4; ++r) {
            float t = fmaxf(fmaxf(sc[0][r], sc[1][r]), fmaxf(sc[2][r], sc[3][r]));
            t = fmaxf(t, __shfl_xor(t, 1));
            t = fmaxf(t, __shfl_xor(t, 2));
            t = fmaxf(t, __shfl_xor(t, 4));
            t = fmaxf(t, __shfl_xor(t, 8));
            const bool upd = t > mrow[r];
            const float mnew = fmaxf(mrow[r], t);
            float ls = 0.f;
#pragma unroll
            for (int jb = 0; jb < 4; ++jb) {
                const float p = fast_exp2(sc[jb][r] - mnew);
                ls += p;
                Ps[w][lg * 4 + r][jb * 16 + l15] = f2bf_hu(p);
            }
            ls += __shfl_xor(ls, 1);
            ls += __shfl_xor(ls, 2);
            ls += __shfl_xor(ls, 4);
            ls += __shfl_xor(ls, 8);
            if (upd) {                       // subgroup-uniform branch (T13-lite)
                const float scl = fast_exp2(mrow[r] - mnew);
                lrow[r] = lrow[r] * scl + ls;
                mrow[r] = mnew;
#pragma unroll
                for (int db = 0; db < 4; ++db) accO[db][r] *= scl;
            } else {
                lrow[r] += ls;
            }
        }

        // PV: accO(16x64) += P_strip @ V_tile
#pragma unroll
        for (int jb2 = 0; jb2 < 2; ++jb2) {
            const bf16x8 pf = *reinterpret_cast<const bf16x8*>(&Ps[w][l15][lg * 8 + jb2 * 32]);
#pragma unroll
            for (int db = 0; db < 4; ++db) {
                const int vr = db * 16 + l15;
                const bf16x8 vf = *reinterpret_cast<const bf16x8*>(&Vs[vr * 64 + ((lg * 8 + jb2 * 32) ^ ((vr & 7) << 3))]);
                accO[db] = __builtin_amdgcn_mfma_f32_16x16x32_bf16(pf, vf, accO[db], 0, 0, 0);
            }
        }
    }

    // epilogue: O[b, s, h*64+d] bf16
#pragma unroll
    for (int r = 0; r < 4; ++r) {
        const float inv = 1.f / lrow[r];
        const size_t orow = ((size_t)b * SEQ + q0 + w * 16 + lg * 4 + r) * HIDDEN + h * HDIM;
#pragma unroll
        for (int db = 0; db < 4; ++db)
            O[orow + db * 16 + l15] = f2bf_hu(accO[db][r] * inv);
    }
}

// ---------------------------------------------------------------------------
extern "C" void kernel_launch(void* const* d_in, const int* in_sizes, int n_in,
                              void* d_out, int out_size, void* d_ws, size_t ws_size,
                              hipStream_t stream)
{
    const float* x  = (const float*)d_in[0];
    const float* Wq = (const float*)d_in[1];
    const float* bq = (const float*)d_in[2];
    const float* Wk = (const float*)d_in[3];
    const float* bk = (const float*)d_in[4];
    const float* Wv = (const float*)d_in[5];
    const float* bv = (const float*)d_in[6];
    const float* Wo = (const float*)d_in[7];
    const float* bo = (const float*)d_in[8];
    float* out = (float*)d_out;

    unsigned short* p = (unsigned short*)d_ws;
    const size_t szX = (size_t)NROWS * HIDDEN;
    const size_t szW = (size_t)HIDDEN * HIDDEN;
    const size_t szH = (size_t)BATCH * NHEADS * SEQ * HDIM;
    unsigned short* xb  = p;              p += szX;
    unsigned short* Wqt = p;              p += szW;
    unsigned short* Wkt = p;              p += szW;
    unsigned short* Wvt = p;              p += szW;
    unsigned short* Wot = p;              p += szW;
    unsigned short* Qb  = p;              p += szH;
    unsigned short* Kb  = p;              p += szH;
    unsigned short* Vtb = p;              p += szH;
    unsigned short* Oab = p;              p += szX;

    cvt_bf16<<<(int)(szX / 4 + 255) / 256, 256, 0, stream>>>(x, xb, (int)(szX / 4));
    dim3 tg(HIDDEN / 64, HIDDEN / 64);
    transpose_cvt<<<tg, 256, 0, stream>>>(Wq, Wqt);
    transpose_cvt<<<tg, 256, 0, stream>>>(Wk, Wkt);
    transpose_cvt<<<tg, 256, 0, stream>>>(Wv, Wvt);
    transpose_cvt<<<tg, 256, 0, stream>>>(Wo, Wot);

    dim3 gg(HIDDEN / 96, NROWS / 64);    // (8, 64) = 512 blocks
    gemm_mfma<<<gg, 256, 0, stream>>>(xb, Wqt, bq, Qb, 0, LOG2E);  // Q pre-scaled
    gemm_mfma<<<gg, 256, 0, stream>>>(xb, Wkt, bk, Kb, 0, 1.0f);
    gemm_mfma<<<gg, 256, 0, stream>>>(xb, Wvt, bv, Vtb, 1, 1.0f);

    attn_mfma<<<dim3(SEQ / 64, NHEADS, BATCH), 256, 0, stream>>>(Qb, Kb, Vtb, Oab);

    gemm_mfma<<<gg, 256, 0, stream>>>(Oab, Wot, bo, out, 2, 1.0f);
}